// Round 3
// baseline (557.299 us; speedup 1.0000x reference)
//
#include <hip/hip_runtime.h>

// Problem constants: x (4, 8192, 512) f32, A/B (512, 64), h0 scalar.
#define NBATCH 4
#define LSEQ   8192
#define CH     512
#define ORDER  64
// Truncated IIR impulse response. Worst-case root radius ~0.954 (5-sigma a_64):
// tail at 256 taps ~6e-6, negligible vs measured 9.8e-4 accumulation error
// and the 5.86e-3 threshold.
#define KTAP   256
#define TB     16            // tap block
#define NB     (KTAP / TB)   // 16 tap blocks, multiple of 4 (slot rotation)
#define RROWS  32            // output rows per thread
#define CPB    256           // channels (=threads) per block

// ---------------------------------------------------------------------------
// Kernel 1: impulse response of H(z) = b(z)/(1 + sum A_i z^-i), KTAP taps.
// h0 folded into tap 0. Written tap-grouped-by-4: kt4[(t/4)*CH*4 + c*4 + t%4]
// so kernel 2 loads 4 taps per thread as one coalesced float4.
// Transposed direct form II, one wave per channel; lane j holds state s_{j+1}.
// ---------------------------------------------------------------------------
__global__ __launch_bounds__(ORDER) void rtf_impulse(const float* __restrict__ A,
                                                     const float* __restrict__ B,
                                                     const float* __restrict__ h0,
                                                     float* __restrict__ kt4) {
    const int c    = blockIdx.x;
    const int lane = threadIdx.x;
    const float a  = A[c * ORDER + lane];
    const float bc = B[c * ORDER + lane];
    const float h0v = h0[0];

    float s = 0.0f;
    for (int t = 0; t < KTAP; ++t) {
        const float s1 = __shfl(s, 0);
        const float bt = (t < ORDER) ? __shfl(bc, t) : 0.0f;
        const float y  = bt + s1;
        float su = __shfl_down(s, 1);
        if (lane == ORDER - 1) su = 0.0f;
        s = su - a * y;
        if (lane == 0)
            kt4[((size_t)(t >> 2) * CH + c) * 4 + (t & 3)] = (t == 0) ? (y + h0v) : y;
    }
}

// ---------------------------------------------------------------------------
// Kernel 2: depthwise causal FIR + tanh-GELU, block-Toeplitz register schedule.
//   out[b,n,c] = gelu( sum_{t<KTAP} K[c,t] x[b,n-t,c] )
// Thread = channel (coalesced), 32 output rows per thread. Taps processed in
// blocks of 16. x lives in 4 rotating 16-row chunks: chunk q holds rows
// n0-16q .. n0-16q+15 in slot q&3. Block m uses chunks {m-1, m, m+1} and
// ISSUES chunk m+2 -> every x load has a full tap-block (~500 instr) of slack
// before first use, vs 1 tap in the old ring design. All slot/component
// indices compile-time via the unroll-by-4 over u=m&3.
// ---------------------------------------------------------------------------
__global__ __launch_bounds__(CPB, 3) void fir_gelu(const float* __restrict__ x,
                                                   const float* __restrict__ kt4,
                                                   float* __restrict__ out) {
    const int c  = blockIdx.y * CPB + threadIdx.x;
    const int n0 = blockIdx.x * RROWS;
    const int b  = blockIdx.z;
    const float* xb = x + (size_t)b * LSEQ * CH + c;

    float  acc[RROWS];
    float  xs[4][TB];      // rotating x chunks, all indices static
    float4 kb[TB / 4];     // current tap block's k values

#pragma unroll
    for (int r = 0; r < RROWS; ++r) acc[r] = 0.0f;

    // prologue: chunks q=-1,0,1 (rows n0+16..31, n0..15, n0-16..-1)
#pragma unroll
    for (int q = -1; q <= 1; ++q) {
#pragma unroll
        for (int i = 0; i < TB; ++i) {
            const int row = n0 - TB * q + i;
            xs[q & 3][i] = (row >= 0) ? xb[(size_t)row * CH] : 0.0f;
        }
    }

    for (int mb = 0; mb < NB; mb += 4) {
#pragma unroll
        for (int u = 0; u < 4; ++u) {
            const int m = mb + u;   // mb%4==0 so (m+k)&3 == (u+k)&3, compile-time
            // k for this tap block: 4 coalesced float4 loads (L2-hot, 512 KB total)
#pragma unroll
            for (int j = 0; j < TB / 4; ++j)
                kb[j] = *(const float4*)&kt4[((size_t)(m * (TB / 4) + j) * CH + c) * 4];
            // issue x chunk q=m+2 into slot (u+2)&3; first used at block m+1
#pragma unroll
            for (int i = 0; i < TB; ++i) {
                const int row = n0 - TB * (m + 2) + i;
                xs[(u + 2) & 3][i] = (row >= 0) ? xb[(size_t)row * CH] : 0.0f;
            }
            // 16 taps x 32 rows = 512 FMAs
#pragma unroll
            for (int g = 0; g < TB; ++g) {
                const float kv = ((const float*)&kb[g >> 2])[g & 3];
#pragma unroll
                for (int r = 0; r < RROWS; ++r) {
                    const int d = r - g;                       // in [-15, 31]
                    const int h = (d >= TB) ? 1 : ((d >= 0) ? 0 : -1);
                    const int i = d - TB * h;                  // 0..15, static
                    acc[r] = fmaf(kv, xs[(u - h) & 3][i], acc[r]);
                }
            }
        }
    }

    float* ob = out + ((size_t)b * LSEQ + n0) * CH + c;
#pragma unroll
    for (int r = 0; r < RROWS; ++r) {
        const float y = acc[r];
        // JAX default gelu (approximate=True)
        const float t = 0.7978845608028654f * (y + 0.044715f * y * y * y);
        ob[(size_t)r * CH] = 0.5f * y * (1.0f + tanhf(t));
    }
}

extern "C" void kernel_launch(void* const* d_in, const int* in_sizes, int n_in,
                              void* d_out, int out_size, void* d_ws, size_t ws_size,
                              hipStream_t stream) {
    const float* x  = (const float*)d_in[0];
    const float* A  = (const float*)d_in[1];
    const float* B  = (const float*)d_in[2];
    const float* h0 = (const float*)d_in[3];
    float* out = (float*)d_out;
    float* kt4 = (float*)d_ws; // (KTAP/4)*CH*4*4B = 512 KB scratch

    rtf_impulse<<<dim3(CH), dim3(ORDER), 0, stream>>>(A, B, h0, kt4);
    fir_gelu<<<dim3(LSEQ / RROWS, CH / CPB, NBATCH), dim3(CPB), 0, stream>>>(x, kt4, out);
}

// Round 4
// 166.938 us; speedup vs baseline: 3.3384x; 3.3384x over previous
//
#include <hip/hip_runtime.h>

// Problem constants: x (4, 8192, 512) f32, A/B (512, 64), h0 scalar.
#define NBATCH 4
#define LSEQ   8192
#define CH     512
#define ORDER  64
// Truncated IIR impulse response. KTAP=256 validated in R3: absmax 9.8e-4
// (identical to KTAP=384), threshold 5.86e-3.
#define KTAP   256
#define RING   32            // output rows per thread / ring size (pow2)
#define CPB    256           // channels (=threads) per block

// ---------------------------------------------------------------------------
// Kernel 1: impulse response of H(z) = b(z)/(1 + sum A_i z^-i), KTAP taps.
// h0 folded into tap 0. Written tap-grouped-by-4: kt4[(t>>2)*CH*4 + c*4 + (t&3)]
// so kernel 2 loads 4 taps per channel as one coalesced float4.
// Transposed direct form II, one wave per channel; lane j holds state s_{j+1}.
// ---------------------------------------------------------------------------
__global__ __launch_bounds__(ORDER) void rtf_impulse(const float* __restrict__ A,
                                                     const float* __restrict__ B,
                                                     const float* __restrict__ h0,
                                                     float* __restrict__ kt4) {
    const int c    = blockIdx.x;
    const int lane = threadIdx.x;
    const float a  = A[c * ORDER + lane];
    const float bc = B[c * ORDER + lane];
    const float h0v = h0[0];

    float s = 0.0f;
    for (int t = 0; t < KTAP; ++t) {
        const float s1 = __shfl(s, 0);
        const float bt = (t < ORDER) ? __shfl(bc, t) : 0.0f;
        const float y  = bt + s1;
        float su = __shfl_down(s, 1);
        if (lane == ORDER - 1) su = 0.0f;
        s = su - a * y;
        if (lane == 0)
            kt4[((size_t)(t >> 2) * CH + c) * 4 + (t & 3)] = (t == 0) ? (y + h0v) : y;
    }
}

// ---------------------------------------------------------------------------
// Kernel 2: depthwise causal FIR + tanh-GELU.
//   out[b,n,c] = gelu( sum_{t<KTAP} K[c,t] * x[b,n-t,c] )   (x[<0]=0)
// R1's proven 32-row register ring + software-pipelined prefetch:
// taps processed in quarters of 8; x rows and k taps for quarter q+1 are
// loaded at the START of quarter q into double-buffered register arrays
// (px[2][8], kbuf[2][8]) -> every load has ~8 taps (~550 cy) of slack before
// first use instead of R1's 1 tap. Tap loop unrolled by 32 so ALL array
// indices (ring slots, buffer selectors) are compile-time. No address-taking
// of locals anywhere (R3's scratch-spill lesson): float4 k loads are assigned
// to named members.
// ---------------------------------------------------------------------------
__global__ __launch_bounds__(CPB) void fir_gelu(const float* __restrict__ x,
                                                const float* __restrict__ kt4,
                                                float* __restrict__ out) {
    const int c  = blockIdx.y * CPB + threadIdx.x;
    const int n0 = blockIdx.x * RING;
    const int b  = blockIdx.z;
    const float* xb = x + (size_t)b * LSEQ * CH + c;
    const float4* kt4v = (const float4*)kt4;   // float4 per (tap group, channel)

    float acc[RING];
    float ring[RING];
    float px[2][8];     // prefetched x rows for the next quarter's insertions
    float kbuf[2][8];   // k taps for current/next quarter

#pragma unroll
    for (int r = 0; r < RING; ++r) acc[r] = 0.0f;
    // ring slot i <- row n0+i  (slot of row m is (m-n0)&31 throughout)
#pragma unroll
    for (int i = 0; i < RING; ++i) ring[i] = xb[(size_t)(n0 + i) * CH];

    // prologue: quarter 0 buffers (taps 0..7)
    {
        const float4 ka = kt4v[(size_t)0 * CH + c];   // taps 0..3
        const float4 kb = kt4v[(size_t)1 * CH + c];   // taps 4..7
        kbuf[0][0] = ka.x; kbuf[0][1] = ka.y; kbuf[0][2] = ka.z; kbuf[0][3] = ka.w;
        kbuf[0][4] = kb.x; kbuf[0][5] = kb.y; kbuf[0][6] = kb.z; kbuf[0][7] = kb.w;
#pragma unroll
        for (int g = 0; g < 8; ++g) {
            const int m = n0 - 1 - g;                 // row inserted at tap g
            px[0][g] = (m >= 0) ? xb[(size_t)m * CH] : 0.0f;
        }
    }

    for (int tb = 0; tb < KTAP; tb += RING) {
#pragma unroll
        for (int q = 0; q < 4; ++q) {
            const int cur = q & 1;
            const int nxt = cur ^ 1;
            const int tn  = tb + 8 * (q + 1);         // next quarter's first tap
            // ---- prefetch next quarter (k: 2x float4; x: 8 rows) ----
            if (tn < KTAP) {
                const float4 ka = kt4v[(size_t)(tn >> 2) * CH + c];
                const float4 kb = kt4v[(size_t)((tn >> 2) + 1) * CH + c];
                kbuf[nxt][0] = ka.x; kbuf[nxt][1] = ka.y;
                kbuf[nxt][2] = ka.z; kbuf[nxt][3] = ka.w;
                kbuf[nxt][4] = kb.x; kbuf[nxt][5] = kb.y;
                kbuf[nxt][6] = kb.z; kbuf[nxt][7] = kb.w;
#pragma unroll
                for (int g = 0; g < 8; ++g) {
                    const int m = n0 - tn - 1 - g;    // row inserted at tap tn+g
                    px[nxt][g] = (m >= 0) ? xb[(size_t)m * CH] : 0.0f;
                }
            }
            // ---- compute taps tb+8q .. tb+8q+7 ----
#pragma unroll
            for (int g = 0; g < 8; ++g) {
                const int tq = 8 * q + g;             // tap index mod 32, static
                const float kv = kbuf[cur][g];
#pragma unroll
                for (int r = 0; r < RING; ++r)
                    acc[r] = fmaf(kv, ring[(r - tq) & (RING - 1)], acc[r]);
                // retire oldest row, insert prefetched row n0-(tb+tq)-1
                ring[(RING - 1 - tq) & (RING - 1)] = px[cur][g];
            }
        }
    }

    float* ob = out + ((size_t)b * LSEQ + n0) * CH + c;
#pragma unroll
    for (int r = 0; r < RING; ++r) {
        const float y = acc[r];
        // JAX default gelu (approximate=True)
        const float u = 0.7978845608028654f * (y + 0.044715f * y * y * y);
        ob[(size_t)r * CH] = 0.5f * y * (1.0f + tanhf(u));
    }
}

extern "C" void kernel_launch(void* const* d_in, const int* in_sizes, int n_in,
                              void* d_out, int out_size, void* d_ws, size_t ws_size,
                              hipStream_t stream) {
    const float* x  = (const float*)d_in[0];
    const float* A  = (const float*)d_in[1];
    const float* B  = (const float*)d_in[2];
    const float* h0 = (const float*)d_in[3];
    float* out = (float*)d_out;
    float* kt4 = (float*)d_ws; // (KTAP/4)*CH*4*4B = 512 KB scratch

    rtf_impulse<<<dim3(CH), dim3(ORDER), 0, stream>>>(A, B, h0, kt4);
    fir_gelu<<<dim3(LSEQ / RING, CH / CPB, NBATCH), dim3(CPB), 0, stream>>>(x, kt4, out);
}

// Round 5
// 145.953 us; speedup vs baseline: 3.8183x; 1.1438x over previous
//
#include <hip/hip_runtime.h>

// Problem constants: x (4, 8192, 512) f32, A/B (512, 64), h0 scalar.
#define NBATCH 4
#define LSEQ   8192
#define CH     512
#define ORDER  64
// Truncated IIR impulse response. KTAP=256 validated: absmax 9.8e-4 (same as
// KTAP=384), threshold 5.86e-3.
#define KTAP   256
#define RING   32            // output rows per thread / ring size (pow2)
#define CPB    256           // channels (=threads) per block

// ---------------------------------------------------------------------------
// Kernel 1: impulse response of H(z) = b(z)/(1 + sum A_i z^-i), KTAP taps.
// h0 folded into tap 0. Written tap-grouped-by-4: kt4[(t>>2)*CH*4 + c*4 + (t&3)]
// so kernel 2 loads 4 taps per channel as one coalesced float4.
// Transposed direct form II, one wave per channel; lane j holds state s_{j+1}.
// ---------------------------------------------------------------------------
__global__ __launch_bounds__(ORDER) void rtf_impulse(const float* __restrict__ A,
                                                     const float* __restrict__ B,
                                                     const float* __restrict__ h0,
                                                     float* __restrict__ kt4) {
    const int c    = blockIdx.x;
    const int lane = threadIdx.x;
    const float a  = A[c * ORDER + lane];
    const float bc = B[c * ORDER + lane];
    const float h0v = h0[0];

    float s = 0.0f;
    for (int t = 0; t < KTAP; ++t) {
        const float s1 = __shfl(s, 0);
        const float bt = (t < ORDER) ? __shfl(bc, t) : 0.0f;
        const float y  = bt + s1;
        float su = __shfl_down(s, 1);
        if (lane == ORDER - 1) su = 0.0f;
        s = su - a * y;
        if (lane == 0)
            kt4[((size_t)(t >> 2) * CH + c) * 4 + (t & 3)] = (t == 0) ? (y + h0v) : y;
    }
}

// ---------------------------------------------------------------------------
// Kernel 2: depthwise causal FIR + tanh-GELU. R4's proven register-ring +
// 8-tap double-buffered prefetch structure (VGPR=100, no spill), plus:
//
// XCD-aware swizzle (T1): grid is 1D (2048 wgs). Hardware round-robins wgs
// across the 8 XCDs (wg%8); we remap so XCD k gets logical ids k*256..k*256+255
// = ALL 256 n-tiles of ONE (batch, channel-half) slab. Consecutive n-tiles
// share 87% of their 288-row x window; with the whole slab on one XCD the
// re-reads hit that XCD's private L2 instead of going to L3/HBM, and no slab
// is fetched by two XCDs. L2 latency (~200cy) << 8-tap prefetch slack (~550cy).
//
// Fast GELU: gelu(y) = 0.5y(1+tanh(u)) == y*e/(e+1) with e=exp(2u) exactly;
// __expf + v_rcp (~9 instr vs ~25 for tanhf). Saturation is naturally correct
// (e->inf => y; e->0 => 0). rcp error ~1e-7 rel, threshold 5.9e-3.
// ---------------------------------------------------------------------------
__global__ __launch_bounds__(CPB) void fir_gelu(const float* __restrict__ x,
                                                const float* __restrict__ kt4,
                                                float* __restrict__ out) {
    const int h       = blockIdx.x;
    const int logical = ((h & 7) << 8) | (h >> 3);   // XCD k <- slab k, tiles in order
    const int tile    = logical & 255;               // n-tile index
    const int sl      = logical >> 8;                // slab 0..7
    const int cb      = sl & 1;                      // channel half
    const int b       = sl >> 1;                     // batch

    const int c  = cb * CPB + threadIdx.x;
    const int n0 = tile * RING;
    const float* xb = x + (size_t)b * LSEQ * CH + c;
    const float4* kt4v = (const float4*)kt4;

    float acc[RING];
    float ring[RING];
    float px[2][8];     // prefetched x rows for the next quarter's insertions
    float kbuf[2][8];   // k taps for current/next quarter

#pragma unroll
    for (int r = 0; r < RING; ++r) acc[r] = 0.0f;
    // ring slot i <- row n0+i  (slot of row m is (m-n0)&31 throughout)
#pragma unroll
    for (int i = 0; i < RING; ++i) ring[i] = xb[(size_t)(n0 + i) * CH];

    // prologue: quarter 0 buffers (taps 0..7)
    {
        const float4 ka = kt4v[(size_t)0 * CH + c];   // taps 0..3
        const float4 kb = kt4v[(size_t)1 * CH + c];   // taps 4..7
        kbuf[0][0] = ka.x; kbuf[0][1] = ka.y; kbuf[0][2] = ka.z; kbuf[0][3] = ka.w;
        kbuf[0][4] = kb.x; kbuf[0][5] = kb.y; kbuf[0][6] = kb.z; kbuf[0][7] = kb.w;
#pragma unroll
        for (int g = 0; g < 8; ++g) {
            const int m = n0 - 1 - g;                 // row inserted at tap g
            px[0][g] = (m >= 0) ? xb[(size_t)m * CH] : 0.0f;
        }
    }

    for (int tb = 0; tb < KTAP; tb += RING) {
#pragma unroll
        for (int q = 0; q < 4; ++q) {
            const int cur = q & 1;
            const int nxt = cur ^ 1;
            const int tn  = tb + 8 * (q + 1);         // next quarter's first tap
            // ---- prefetch next quarter (k: 2x float4; x: 8 rows) ----
            if (tn < KTAP) {
                const float4 ka = kt4v[(size_t)(tn >> 2) * CH + c];
                const float4 kb = kt4v[(size_t)((tn >> 2) + 1) * CH + c];
                kbuf[nxt][0] = ka.x; kbuf[nxt][1] = ka.y;
                kbuf[nxt][2] = ka.z; kbuf[nxt][3] = ka.w;
                kbuf[nxt][4] = kb.x; kbuf[nxt][5] = kb.y;
                kbuf[nxt][6] = kb.z; kbuf[nxt][7] = kb.w;
#pragma unroll
                for (int g = 0; g < 8; ++g) {
                    const int m = n0 - tn - 1 - g;    // row inserted at tap tn+g
                    px[nxt][g] = (m >= 0) ? xb[(size_t)m * CH] : 0.0f;
                }
            }
            // ---- compute taps tb+8q .. tb+8q+7 ----
#pragma unroll
            for (int g = 0; g < 8; ++g) {
                const int tq = 8 * q + g;             // tap index mod 32, static
                const float kv = kbuf[cur][g];
#pragma unroll
                for (int r = 0; r < RING; ++r)
                    acc[r] = fmaf(kv, ring[(r - tq) & (RING - 1)], acc[r]);
                // retire oldest row, insert prefetched row n0-(tb+tq)-1
                ring[(RING - 1 - tq) & (RING - 1)] = px[cur][g];
            }
        }
    }

    float* ob = out + ((size_t)b * LSEQ + n0) * CH + c;
#pragma unroll
    for (int r = 0; r < RING; ++r) {
        const float y = acc[r];
        // gelu(y) = y * e/(e+1), e = exp(2*0.79788456*(y + 0.044715 y^3))
        const float m2 = y * y;
        const float w  = fmaf(m2, 0.14270963f, 1.5957691f);   // 2*C1*C2, 2*C1
        const float e  = __expf(y * w);
        const float r1 = __builtin_amdgcn_rcpf(e + 1.0f);
        ob[(size_t)r * CH] = y - y * r1;                      // y*e/(e+1)
    }
}

extern "C" void kernel_launch(void* const* d_in, const int* in_sizes, int n_in,
                              void* d_out, int out_size, void* d_ws, size_t ws_size,
                              hipStream_t stream) {
    const float* x  = (const float*)d_in[0];
    const float* A  = (const float*)d_in[1];
    const float* B  = (const float*)d_in[2];
    const float* h0 = (const float*)d_in[3];
    float* out = (float*)d_out;
    float* kt4 = (float*)d_ws; // (KTAP/4)*CH*4*4B = 512 KB scratch

    rtf_impulse<<<dim3(CH), dim3(ORDER), 0, stream>>>(A, B, h0, kt4);
    // 1D grid: 256 n-tiles x 2 channel-halves x 4 batches, XCD-swizzled in-kernel
    fir_gelu<<<dim3((LSEQ / RING) * (CH / CPB) * NBATCH), dim3(CPB), 0, stream>>>(x, kt4, out);
}